// Round 19
// baseline (568.100 us; speedup 1.0000x reference)
//
#include <hip/hip_runtime.h>
#include <math.h>

// EGAT GNN forward — round 21: R20 base (measured 563.6us; score32 reproduced
// 51.5us/52VGPR) + node_fused with 2x memory-level parallelism.
// R20 post-mortem: single-barrier gemm_agg NEUTRAL (563.6 vs 560.8, noise) ->
// gemm_agg's barrier chain wasn't the cost; kept (simpler, measured-equal).
// Per pre-commit, pivot to node_fused: it moves ~75MB/dispatch (41MB random
// 128B hsrc gathers + 25.6MB zb writes) through a SERIAL per-node degree loop
// with only 4 independent node-loops per wave (16-lane groups). Fix: 8-lane
// groups (uint4 h-loads, 16B/lane) -> 8 independent degree loops per wave
// (2x gather MLP) + unroll 4. Per output element the fmaf sequence is
// identical (same order, same operands; only lane->dim assignment changes)
// -> bit-identical zb, absmax unchanged.
#define NN 50000      // N_NODES
#define NE 320000     // N_EDGES
#define BATCH 4096

typedef __bf16 bf16x8 __attribute__((ext_vector_type(8)));
typedef float floatx4 __attribute__((ext_vector_type(4)));
typedef float floatx16 __attribute__((ext_vector_type(16)));
typedef unsigned short ushort;
typedef unsigned int uint;

__device__ __forceinline__ float lrelu02(float x) { return x > 0.f ? x : 0.2f * x; }
__device__ __forceinline__ float b2f(ushort h) { return __uint_as_float(((uint)h) << 16); }
__device__ __forceinline__ float b2f_lo(uint u) { return __uint_as_float(u << 16); }
__device__ __forceinline__ float b2f_hi(uint u) { return __uint_as_float(u & 0xffff0000u); }
__device__ __forceinline__ ushort f2b(float x) {
    uint u = __float_as_uint(x);
    return (ushort)((u + 0x7fffu + ((u >> 16) & 1u)) >> 16);  // RNE
}
__device__ __forceinline__ uint pk2(float a, float b) {
    return (uint)f2b(a) | ((uint)f2b(b) << 16);
}

// ---------------------------------------------------------------------------
// 32x32x16 transposed score kernel, original edge order (EXACT R16, frozen).
// Per wave: 32 edges. A = weights [we|wni|wnj] (128 f-dims x KTOT), LDS,
// fragment-ordered, staged once per block. B = [ef | h[src] | h[dst]]:
// per-lane 16B bf16 k-fragments (k = 16t + 8*(lane>>5) + j), edge n=lane&31.
// All global loads issued before the single barrier. ctile c == head c: acc
// row = (reg&3)+8*(reg>>2)+4*hi (m74/m101-verified C/D layout). One ctile
// acc live at a time. Coalesced scv write at original edge index.
// ---------------------------------------------------------------------------
template <int GLOB>
__global__ __launch_bounds__(512, 4) void score32(
    const float* __restrict__ ef,       // E x (GLOB?64:16) fp32, original order
    const ushort* __restrict__ Bfrag,   // fragment-ordered weights, 128*KTOT
    const ushort* __restrict__ hb,      // N x 64 bf16 layer input
    const int* __restrict__ srcv, const int* __restrict__ dstv,
    const float* __restrict__ attn, float* __restrict__ scv)
{
    constexpr int NK = GLOB ? 12 : 9;    // k-steps of 16: ef(4|1)+wni(4)+wnj(4)
    constexpr int KTOT = NK * 16;        // 192 / 144
    constexpr int EFR = GLOB ? 4 : 1;    // ef k-fragments
    constexpr int LDA = GLOB ? 64 : 16;
    __shared__ __align__(16) ushort As[128 * KTOT];
    const int tid = threadIdx.x;
    const int wid = tid >> 6, lane = tid & 63;
    const int hi = lane >> 5;            // k-half
    const int row = (blockIdx.x << 8) + (wid << 5) + (lane & 31);  // edge

    const int s_n = srcv[row];
    const int d_n = dstv[row];

    // B-operand fragments, all issued before the barrier
    bf16x8 bfr[NK];
#pragma unroll
    for (int t = 0; t < EFR; t++) {
        const float* ap = ef + (size_t)row * LDA + t * 16 + hi * 8;
        float4 f0 = *(const float4*)ap;
        float4 f1 = *(const float4*)(ap + 4);
        uint4 av;
        av.x = pk2(f0.x, f0.y); av.y = pk2(f0.z, f0.w);
        av.z = pk2(f1.x, f1.y); av.w = pk2(f1.z, f1.w);
        *(uint4*)&bfr[t] = av;
    }
#pragma unroll
    for (int t = 0; t < 4; t++)
        bfr[EFR + t] = *(const bf16x8*)(hb + (size_t)s_n * 64 + t * 16 + hi * 8);
#pragma unroll
    for (int t = 0; t < 4; t++)
        bfr[EFR + 4 + t] = *(const bf16x8*)(hb + (size_t)d_n * 64 + t * 16 + hi * 8);

    // stage fragment-ordered weights (straight copy, once per block)
    for (int i = tid; i < 128 * KTOT / 8; i += 512)
        *(uint4*)(As + (size_t)i * 8) = *(const uint4*)(Bfrag + (size_t)i * 8);
    __syncthreads();

    float ph[4];
#pragma unroll
    for (int c = 0; c < 4; c++) {        // ctile c == head c (32 f-dims)
        floatx16 acc;
#pragma unroll
        for (int r = 0; r < 16; r++) acc[r] = 0.f;
#pragma unroll
        for (int t = 0; t < NK; t++) {
            bf16x8 afr = *(const bf16x8*)(As + ((size_t)(c * NK + t) * 64 + lane) * 8);
            acc = __builtin_amdgcn_mfma_f32_32x32x16_bf16(afr, bfr[t], acc, 0, 0, 0);
        }
        // epilogue: row = (reg&3) + 8*(reg>>2) + 4*hi; attn flat 128
        float v = 0.f;
#pragma unroll
        for (int q = 0; q < 4; q++) {
            float4 at4 = *(const float4*)(attn + c * 32 + hi * 4 + q * 8);
            v = fmaf(lrelu02(acc[q * 4 + 0]), at4.x, v);
            v = fmaf(lrelu02(acc[q * 4 + 1]), at4.y, v);
            v = fmaf(lrelu02(acc[q * 4 + 2]), at4.z, v);
            v = fmaf(lrelu02(acc[q * 4 + 3]), at4.w, v);
        }
        ph[c] = v;
    }
#pragma unroll
    for (int h = 0; h < 4; h++) ph[h] += __shfl_xor(ph[h], 32);
    if (hi == 0)
        *(float4*)(scv + (size_t)row * 4) = make_float4(ph[0], ph[1], ph[2], ph[3]);
}

// ---------------------------------------------------------------------------
// Aggregation GEMM, single-barrier (R20, measured-neutral vs 16-barrier):
// z (M x 256 bf16) @ Bfold^T -> act -> M x 64. Bfold staged to LDS once
// (rows padded to 264); A-row fragments direct from global pre-barrier.
// ---------------------------------------------------------------------------
__global__ __launch_bounds__(256) void gemm_agg(
    const ushort* __restrict__ A, int M,
    const ushort* __restrict__ Bt,    // 64 x 256
    const float* __restrict__ bias, int act,
    ushort* __restrict__ outb)
{
    __shared__ __align__(16) ushort Bs[64 * 264];   // +8/row pad
    const int tid = threadIdx.x;
    const int row0 = blockIdx.x << 6;
    const int w = tid >> 6, lane = tid & 63;
    const int quad = lane >> 4, l16 = lane & 15;
    const int arow = row0 + 16 * w + l16;

    // stage full B once (coalesced 16B copies into padded rows)
    for (int idx = tid; idx < 64 * 32; idx += 256) {
        int r = idx >> 5, c8 = (idx & 31) << 3;
        *(uint4*)(Bs + r * 264 + c8) = *(const uint4*)(Bt + (size_t)r * 256 + c8);
    }

    // A-row fragments direct from global (pre-barrier; 8 independent loads)
    bf16x8 afr[8];
#pragma unroll
    for (int kt = 0; kt < 8; kt++) {
        uint4 av = make_uint4(0u, 0u, 0u, 0u);
        if (arow < M)
            av = *(const uint4*)(A + (size_t)arow * 256 + kt * 32 + quad * 8);
        *(uint4*)&afr[kt] = av;
    }
    __syncthreads();

    floatx4 acc[4];
#pragma unroll
    for (int c = 0; c < 4; c++)
#pragma unroll
        for (int r = 0; r < 4; r++) acc[c][r] = 0.f;

#pragma unroll
    for (int kt = 0; kt < 8; kt++) {
#pragma unroll
        for (int c = 0; c < 4; c++) {
            bf16x8 bfv = *(const bf16x8*)(Bs + (16 * c + l16) * 264 + kt * 32 + quad * 8);
            acc[c] = __builtin_amdgcn_mfma_f32_16x16x32_bf16(afr[kt], bfv, acc[c], 0, 0, 0);
        }
    }
#pragma unroll
    for (int r = 0; r < 4; r++) {
        int gr = row0 + 16 * w + quad * 4 + r;
        if (gr < M) {
#pragma unroll
            for (int c = 0; c < 4; c++) {
                int col = 16 * c + l16;
                float v = acc[c][r] + bias[col];
                if (act == 0) v = v > 0.f ? v : (__expf(v) - 1.f);
                else          v = v > 0.f ? v : 0.01f * v;
                outb[(size_t)gr * 64 + col] = f2b(v);
            }
        }
    }
}

// ---------------------------------------------------------------------------
// Deterministic CSR build: histogram -> scan -> atomic rank scatter (eidx only)
// -> per-node insertion sort (original-index order).
// ---------------------------------------------------------------------------
__global__ void k_count(const int* __restrict__ dst, int* __restrict__ deg, int E)
{
    for (int i = blockIdx.x * blockDim.x + threadIdx.x; i < E; i += gridDim.x * blockDim.x)
        atomicAdd(&deg[dst[i]], 1);
}

__global__ __launch_bounds__(256) void scan_local(
    const int* __restrict__ deg, int* __restrict__ rowptr, int* __restrict__ partials, int N)
{
    __shared__ int sd[256];
    int tid = threadIdx.x;
    int i = blockIdx.x * 256 + tid;
    int v = (i < N) ? deg[i] : 0;
    sd[tid] = v; __syncthreads();
#pragma unroll
    for (int off = 1; off < 256; off <<= 1) {
        int t = (tid >= off) ? sd[tid - off] : 0;
        __syncthreads();
        sd[tid] += t;
        __syncthreads();
    }
    if (i < N) rowptr[i] = sd[tid] - v;
    if (tid == 255) partials[blockIdx.x] = sd[255];
}

__global__ __launch_bounds__(256) void scan_partials(int* __restrict__ partials, int nb)
{
    __shared__ int sd[256];
    int tid = threadIdx.x;
    int v = (tid < nb) ? partials[tid] : 0;
    sd[tid] = v; __syncthreads();
#pragma unroll
    for (int off = 1; off < 256; off <<= 1) {
        int t = (tid >= off) ? sd[tid - off] : 0;
        __syncthreads();
        sd[tid] += t;
        __syncthreads();
    }
    if (tid < nb) partials[tid] = sd[tid] - v;
}

__global__ void scan_add(int* __restrict__ rowptr, const int* __restrict__ partials, int N, int E)
{
    int i = blockIdx.x * 256 + threadIdx.x;
    if (i < N) rowptr[i] += partials[i >> 8];
    if (i == 0) rowptr[N] = E;
}

__global__ void k_scatter(const int* __restrict__ dst, const int* __restrict__ rowptr,
                          int* __restrict__ cnt, int* __restrict__ eidx, int E)
{
    for (int i = blockIdx.x * blockDim.x + threadIdx.x; i < E; i += gridDim.x * blockDim.x) {
        int d = dst[i];
        int p = rowptr[d] + atomicAdd(&cnt[d], 1);
        eidx[p] = i;
    }
}

// one thread per node: insertion-sort its bucket ascending (deterministic,
// matches reference's index-order segment sums). Avg degree 6.4.
__global__ void k_sort_buckets(const int* __restrict__ rowptr, int* __restrict__ eidx, int N)
{
    int n = blockIdx.x * blockDim.x + threadIdx.x;
    if (n >= N) return;
    int beg = rowptr[n], end = rowptr[n + 1];
    for (int i = beg + 1; i < end; i++) {
        int v = eidx[i];
        int j = i - 1;
        while (j >= beg && eidx[j] > v) { eidx[j + 1] = eidx[j]; j--; }
        eidx[j + 1] = v;
    }
}

// small permute: per CSR position p, pull src/masks (L2-resident gathers).
__global__ void k_perm_small(const int* __restrict__ eidx, const int* __restrict__ src,
                             const float* __restrict__ m1, const float* __restrict__ m2,
                             int* __restrict__ srcp, float* __restrict__ m1p,
                             float* __restrict__ m2p, int E)
{
    int p = blockIdx.x * blockDim.x + threadIdx.x;
    if (p < E) {
        int e = eidx[p];
        srcp[p] = src[e];
        m1p[p] = m1[e];
        m2p[p] = m2[e];
    }
}

__global__ void k_cvt(const float* __restrict__ in, ushort* __restrict__ out, int n)
{
    for (int i = blockIdx.x * blockDim.x + threadIdx.x; i < n; i += gridDim.x * blockDim.x)
        out[i] = f2b(in[i]);
}

// ---------------------------------------------------------------------------
// Weight prep for the 32x32x16 score kernel. Bsc[e] fragment order: out index
// o -> j=o&7, lane=(o>>3)&63, tf=o>>9, c=tf/NK, t=tf%NK; m=32c+(lane&31),
// k=16t+8*(lane>>5)+j. Columns: [we(ef_end)|wni(64)|wnj(64)].
// glob: NK=12 (KTOT 192); loc: NK=9 (KTOT 144, no pad).
// ---------------------------------------------------------------------------
__global__ void k_prep_score_all(const float* __restrict__ loc_we, const float* __restrict__ glob_we,
                                 const float* __restrict__ loc_wni, const float* __restrict__ glob_wni,
                                 const float* __restrict__ loc_wnj, const float* __restrict__ glob_wnj,
                                 ushort* __restrict__ B)   // 4 x 24576 slots
{
    int idx = blockIdx.x * 256 + threadIdx.x;   // 4*24576 = 98304
    if (idx >= 4 * 24576) return;
    int e = idx / 24576, rem = idx % 24576;
    int layer = e >> 1, gl = e & 1;
    int NK = gl ? 12 : 9;
    int KTOT = NK * 16;
    int ef_end = gl ? 64 : 16;
    if (rem >= 128 * KTOT) return;
    int j = rem & 7, lane = (rem >> 3) & 63, tf = rem >> 9;
    int c = tf / NK, t = tf % NK;
    int m = 32 * c + (lane & 31);
    int k = 16 * t + 8 * (lane >> 5) + j;
    const float* we  = (gl ? glob_we  + layer * 64 * 128 : loc_we  + layer * 16 * 128);
    const float* wni = (gl ? glob_wni : loc_wni) + layer * 64 * 128;
    const float* wnj = (gl ? glob_wnj : loc_wnj) + layer * 64 * 128;
    float v;
    if (k < ef_end)            v = we[k * 128 + m];
    else if (k < ef_end + 64)  v = wni[(k - ef_end) * 128 + m];
    else                       v = wnj[(k - ef_end - 64) * 128 + m];
    B[e * 24576 + rem] = f2b(v);
}

// W'[h*64+i, j] = sum_k wnode[i, h*64+k] * aggw[h*64+k, j]; stored transposed (64 x 256)
__global__ void k_fold_all(const float* __restrict__ loc_wnode, const float* __restrict__ agg1_w,
                           const float* __restrict__ glob_wnode, const float* __restrict__ agg2_w,
                           ushort* __restrict__ B)  // 4 x (64 x 256)
{
    int e = blockIdx.x >> 6;
    int idx = (blockIdx.x & 63) * 256 + threadIdx.x;  // 16384
    int layer = e >> 1, gl = e & 1;
    const float* wnode = (gl ? glob_wnode : loc_wnode) + layer * 64 * 256;
    const float* aggw  = (gl ? agg2_w : agg1_w) + layer * 256 * 64;
    int j = idx >> 8, col = idx & 255;
    int h = col >> 6, ii = col & 63;
    float s = 0.f;
#pragma unroll 8
    for (int k = 0; k < 64; k++)
        s = fmaf(wnode[ii * 256 + h * 64 + k], aggw[(h * 64 + k) * 64 + j], s);
    B[e * 16384 + j * 256 + col] = f2b(s);
}

// ---------------------------------------------------------------------------
// Node kernel, 8-lane groups (R21): one 8-lane group per node (all 4 heads,
// 16B uint4 h-loads per lane), 32 groups per block -> 8 independent degree
// loops per wave (2x the gather MLP of the 16-lane version) + unroll 4.
// Per output element the fmaf order/operands are identical to the 16-lane
// version -> bit-identical zb.
// ---------------------------------------------------------------------------
__global__ __launch_bounds__(256) void node_fused(
    const float* __restrict__ scv,      // E x 4 fp32 (ORIGINAL edge order)
    const int* __restrict__ eidx,       // CSR position -> original edge
    const int* __restrict__ rowptr, const int* __restrict__ srcp,
    const float* __restrict__ maskp,
    const ushort* __restrict__ hsrc,    // N x 64 bf16 (layer input)
    ushort* __restrict__ zb)            // N x 256 bf16
{
    int tid = threadIdx.x;
    int n = (blockIdx.x << 5) | (tid >> 3);   // 32 groups/block, one node each
    int sl = tid & 7;                          // lane owns dims sl*8..sl*8+7
    if (n >= NN) return;
    int beg = rowptr[n], end = rowptr[n + 1];
    float l0 = 0.f, l1 = 0.f, l2 = 0.f, l3 = 0.f;
    float acc[4][8] = {};
#pragma unroll 4
    for (int i = beg; i < end; i++) {
        int ep = eidx[i];                                    // broadcast in group
        float4 s4 = *(const float4*)(scv + (size_t)ep * 4);  // L2-resident
        float mk = maskp[i];
        int s = srcp[i];
        uint4 hvv = *(const uint4*)(hsrc + (size_t)s * 64 + sl * 8);  // 128B/group
        float t0 = __expf(s4.x), t1 = __expf(s4.y), t2 = __expf(s4.z), t3 = __expf(s4.w);
        l0 += t0; l1 += t1; l2 += t2; l3 += t3;
        float a0 = t0 * mk, a1 = t1 * mk, a2 = t2 * mk, a3 = t3 * mk;
        float hv[8] = { b2f_lo(hvv.x), b2f_hi(hvv.x), b2f_lo(hvv.y), b2f_hi(hvv.y),
                        b2f_lo(hvv.z), b2f_hi(hvv.z), b2f_lo(hvv.w), b2f_hi(hvv.w) };
#pragma unroll
        for (int c = 0; c < 8; c++) {
            acc[0][c] = fmaf(a0, hv[c], acc[0][c]);
            acc[1][c] = fmaf(a1, hv[c], acc[1][c]);
            acc[2][c] = fmaf(a2, hv[c], acc[2][c]);
            acc[3][c] = fmaf(a3, hv[c], acc[3][c]);
        }
    }
    float inv[4] = { 1.f / (l0 + 1e-9f), 1.f / (l1 + 1e-9f),
                     1.f / (l2 + 1e-9f), 1.f / (l3 + 1e-9f) };
#pragma unroll
    for (int h = 0; h < 4; h++) {
        uint4 o;
        o.x = pk2(acc[h][0] * inv[h], acc[h][1] * inv[h]);
        o.y = pk2(acc[h][2] * inv[h], acc[h][3] * inv[h]);
        o.z = pk2(acc[h][4] * inv[h], acc[h][5] * inv[h]);
        o.w = pk2(acc[h][6] * inv[h], acc[h][7] * inv[h]);
        *(uint4*)(zb + (size_t)n * 256 + h * 64 + sl * 8) = o;
    }
}

// ---------------------------------------------------------------------------
// Final MLP heads. One wave per batch row.
// ---------------------------------------------------------------------------
__global__ __launch_bounds__(256) void final_ui(
    const ushort* __restrict__ s0, const ushort* __restrict__ s1,
    const int* __restrict__ uidx, const int* __restrict__ iidx,
    const float* __restrict__ w1, const float* __restrict__ b1,
    const float* __restrict__ w2, const float* __restrict__ b2, float* __restrict__ out)
{
    __shared__ float xs[4][256];
    int tid = threadIdx.x, wid = tid >> 6, lane = tid & 63;
    int r = (blockIdx.x << 2) + wid;
    int u = uidx[r], it = iidx[r];
    xs[wid][lane]       = b2f(s0[(size_t)u * 64 + lane]);
    xs[wid][64 + lane]  = b2f(s1[(size_t)u * 64 + lane]);
    xs[wid][128 + lane] = b2f(s0[(size_t)it * 64 + lane]);
    xs[wid][192 + lane] = b2f(s1[(size_t)it * 64 + lane]);
    __syncthreads();
    int c = lane << 1;
    float a0 = b1[c], a1 = b1[c + 1];
    for (int k = 0; k < 256; k++) {
        float xv = xs[wid][k];
        float2 wv = *(const float2*)(w1 + (size_t)k * 128 + c);
        a0 = fmaf(xv, wv.x, a0);
        a1 = fmaf(xv, wv.y, a1);
    }
    a0 = fmaxf(a0, 0.f);
    a1 = fmaxf(a1, 0.f);
    float2 w2v = *(const float2*)(w2 + c);
    float p = a0 * w2v.x + a1 * w2v.y;
#pragma unroll
    for (int mm = 1; mm < 64; mm <<= 1) p += __shfl_xor(p, mm);
    if (lane == 0) out[r] = 1.f / (1.f + __expf(-(p + b2[0])));
}

__global__ __launch_bounds__(256) void final_sg(
    const ushort* __restrict__ s0, const ushort* __restrict__ s1,
    const int* __restrict__ gidx,
    const float* __restrict__ w1, const float* __restrict__ b1,
    const float* __restrict__ w2, const float* __restrict__ b2, float* __restrict__ out)
{
    __shared__ float xs[4][128];
    int tid = threadIdx.x, wid = tid >> 6, lane = tid & 63;
    int r = (blockIdx.x << 2) + wid;
    int n = gidx[r];
    xs[wid][lane]      = b2f(s0[(size_t)n * 64 + lane]);
    xs[wid][64 + lane] = b2f(s1[(size_t)n * 64 + lane]);
    __syncthreads();
    int c = lane << 1;
    float a0 = b1[c], a1 = b1[c + 1];
    for (int k = 0; k < 128; k++) {
        float xv = xs[wid][k];
        float2 wv = *(const float2*)(w1 + (size_t)k * 128 + c);
        a0 = fmaf(xv, wv.x, a0);
        a1 = fmaf(xv, wv.y, a1);
    }
    a0 = fmaxf(a0, 0.f);
    a1 = fmaxf(a1, 0.f);
    float2 w2v = *(const float2*)(w2 + c);
    float p = a0 * w2v.x + a1 * w2v.y;
#pragma unroll
    for (int mm = 1; mm < 64; mm <<= 1) p += __shfl_xor(p, mm);
    if (lane == 0) out[r] = 1.f / (1.f + __expf(-(p + b2[0])));
}

// ---------------------------------------------------------------------------
extern "C" void kernel_launch(void* const* d_in, const int* in_sizes, int n_in,
                              void* d_out, int out_size, void* d_ws, size_t ws_size,
                              hipStream_t stream)
{
    const float* x       = (const float*)d_in[0];
    const float* efeat   = (const float*)d_in[1];
    const float* efeat2  = (const float*)d_in[2];
    const float* mask1   = (const float*)d_in[3];
    const float* mask2   = (const float*)d_in[4];
    const int*   src     = (const int*)d_in[5];
    const int*   dst     = (const int*)d_in[6];
    const int*   uidx    = (const int*)d_in[7];
    const int*   iidx    = (const int*)d_in[8];
    const int*   gidx    = (const int*)d_in[9];
    const float* loc_wni = (const float*)d_in[10];
    const float* loc_wnj = (const float*)d_in[11];
    const float* loc_we  = (const float*)d_in[12];
    const float* loc_attn= (const float*)d_in[13];
    const float* loc_wnode=(const float*)d_in[14];
    const float* agg1_w  = (const float*)d_in[15];
    const float* agg1_b  = (const float*)d_in[16];
    const float* glob_wni= (const float*)d_in[17];
    const float* glob_wnj= (const float*)d_in[18];
    const float* glob_we = (const float*)d_in[19];
    const float* glob_attn=(const float*)d_in[20];
    const float* glob_wnode=(const float*)d_in[21];
    const float* agg2_w  = (const float*)d_in[22];
    const float* agg2_b  = (const float*)d_in[23];
    const float* w1_ui   = (const float*)d_in[24];
    const float* b1_ui   = (const float*)d_in[25];
    const float* w1_sg   = (const float*)d_in[26];
    const float* b1_sg   = (const float*)d_in[27];
    const float* w2_ui   = (const float*)d_in[28];
    const float* b2_ui   = (const float*)d_in[29];
    const float* w2_sg   = (const float*)d_in[30];
    const float* b2_sg   = (const float*)d_in[31];

    // workspace carve (all offsets 256B-aligned)
    char* wsp = (char*)d_ws;
    auto carve = [&](size_t bytes) { char* p = wsp; wsp += (bytes + 255) & ~(size_t)255; return p; };
    ushort* zb    = (ushort*)carve((size_t)NN * 256 * 2);
    ushort* hb[5];
    for (int i = 0; i < 5; i++) hb[i] = (ushort*)carve((size_t)NN * 64 * 2);
    float*  scv   = (float*)carve((size_t)NE * 16);
    float*  m1p   = (float*)carve((size_t)NE * 4);
    float*  m2p   = (float*)carve((size_t)NE * 4);
    int*    srcp  = (int*)carve((size_t)NE * 4);
    int*    eidx  = (int*)carve((size_t)NE * 4);
    ushort* Bsc   = (ushort*)carve(4 * 24576 * 2);
    ushort* Bfold = (ushort*)carve(4 * 16384 * 2);
    int* deg      = (int*)carve(NN * 4);
    int* rowptr   = (int*)carve((NN + 4) * 4);
    int* partials = (int*)carve(256 * 4);

    // ---- weight prep (state-independent) + deterministic CSR build ----
    k_prep_score_all<<<384, 256, 0, stream>>>(loc_we, glob_we, loc_wni, glob_wni,
                                              loc_wnj, glob_wnj, Bsc);
    k_fold_all<<<256, 256, 0, stream>>>(loc_wnode, agg1_w, glob_wnode, agg2_w, Bfold);
    hipMemsetAsync(deg, 0, NN * sizeof(int), stream);
    k_count<<<1280, 256, 0, stream>>>(dst, deg, NE);
    scan_local<<<196, 256, 0, stream>>>(deg, rowptr, partials, NN);
    scan_partials<<<1, 256, 0, stream>>>(partials, 196);
    scan_add<<<196, 256, 0, stream>>>(rowptr, partials, NN, NE);
    hipMemsetAsync(deg, 0, NN * sizeof(int), stream);
    k_scatter<<<1280, 256, 0, stream>>>(dst, rowptr, deg, eidx, NE);
    k_sort_buckets<<<196, 256, 0, stream>>>(rowptr, eidx, NN);
    k_perm_small<<<1250, 256, 0, stream>>>(eidx, src, mask1, mask2,
                                           srcp, m1p, m2p, NE);
    k_cvt<<<3200, 256, 0, stream>>>(x, hb[0], NN * 64);

    auto egat = [&](const ushort* hin, int e, const float* maskp, const float* attn,
                    const float* aggb, int act, ushort* hout) {
        int is_glob = e & 1;
        if (is_glob)
            score32<1><<<1250, 512, 0, stream>>>(efeat2, Bsc + e * 24576, hin,
                                                 src, dst, attn, scv);
        else
            score32<0><<<1250, 512, 0, stream>>>(efeat, Bsc + e * 24576, hin,
                                                 src, dst, attn, scv);
        node_fused<<<(NN + 31) / 32, 256, 0, stream>>>(scv, eidx, rowptr, srcp, maskp, hin, zb);
        gemm_agg<<<782, 256, 0, stream>>>(zb, NN, Bfold + e * 16384, aggb, act, hout);
    };

    egat(hb[0], 0, m1p, loc_attn,        agg1_b,      0, hb[1]);
    egat(hb[1], 1, m2p, glob_attn,       agg2_b,      1, hb[2]);
    egat(hb[2], 2, m1p, loc_attn + 128,  agg1_b + 64, 0, hb[3]);
    egat(hb[3], 3, m2p, glob_attn + 128, agg2_b + 64, 1, hb[4]);

    float* out = (float*)d_out;
    final_sg<<<BATCH / 4, 256, 0, stream>>>(hb[2], hb[4], gidx, w1_sg, b1_sg, w2_sg, b2_sg, out);
    final_ui<<<BATCH / 4, 256, 0, stream>>>(hb[1], hb[3], uidx, iidx, w1_ui, b1_ui, w2_ui, b2_ui, out + BATCH);
}

// Round 20
// 545.773 us; speedup vs baseline: 1.0409x; 1.0409x over previous
//
#include <hip/hip_runtime.h>
#include <math.h>

// EGAT GNN forward — round 22: fuse node_fused + gemm_agg (zb stays in LDS).
// R21 post-mortem: 8-lane node_fused NEUTRAL (568.1 vs 563.6, within the
// 560.8-568.1 noise band) -- node_fused isn't individually dominant. Two
// neutral probes say the ~360us outside score32 is SPREAD across 8 sub-50us
// kernels + prep + ~22 launch gaps. Fix: node_fused and gemm_agg are a
// producer-consumer pair through zb (25.6MB write + 25.6MB read + launch
// boundary + dependency drain, x4). Fused node_gemm: 512-thread block owns
// 64 nodes; phase1 = R21's 8-lane node structure writing bf16 z to LDS
// Zs[64][264]; Bfold staged to Bs[64][264] concurrently; ONE barrier;
// phase2 = R20's MFMA gemm reading A from Zs (2-way bank alias, free),
// 8 waves = 4 row-blocks x 2 ctile-pairs. Deletes 204MB zb round-trip,
// 8 launches, 4 drains. Bit-exact: same fmaf order + f2b bits in phase1
// (R21-verified), same kt-ascending gemm accumulation; invalid rows
// zero-filled + write-guarded.
#define NN 50000      // N_NODES
#define NE 320000     // N_EDGES
#define BATCH 4096

typedef __bf16 bf16x8 __attribute__((ext_vector_type(8)));
typedef float floatx4 __attribute__((ext_vector_type(4)));
typedef float floatx16 __attribute__((ext_vector_type(16)));
typedef unsigned short ushort;
typedef unsigned int uint;

__device__ __forceinline__ float lrelu02(float x) { return x > 0.f ? x : 0.2f * x; }
__device__ __forceinline__ float b2f(ushort h) { return __uint_as_float(((uint)h) << 16); }
__device__ __forceinline__ float b2f_lo(uint u) { return __uint_as_float(u << 16); }
__device__ __forceinline__ float b2f_hi(uint u) { return __uint_as_float(u & 0xffff0000u); }
__device__ __forceinline__ ushort f2b(float x) {
    uint u = __float_as_uint(x);
    return (ushort)((u + 0x7fffu + ((u >> 16) & 1u)) >> 16);  // RNE
}
__device__ __forceinline__ uint pk2(float a, float b) {
    return (uint)f2b(a) | ((uint)f2b(b) << 16);
}

// ---------------------------------------------------------------------------
// 32x32x16 transposed score kernel, original edge order (EXACT R16, frozen).
// Per wave: 32 edges. A = weights [we|wni|wnj] (128 f-dims x KTOT), LDS,
// fragment-ordered, staged once per block. B = [ef | h[src] | h[dst]]:
// per-lane 16B bf16 k-fragments (k = 16t + 8*(lane>>5) + j), edge n=lane&31.
// All global loads issued before the single barrier. ctile c == head c: acc
// row = (reg&3)+8*(reg>>2)+4*hi (m74/m101-verified C/D layout). One ctile
// acc live at a time. Coalesced scv write at original edge index.
// ---------------------------------------------------------------------------
template <int GLOB>
__global__ __launch_bounds__(512, 4) void score32(
    const float* __restrict__ ef,       // E x (GLOB?64:16) fp32, original order
    const ushort* __restrict__ Bfrag,   // fragment-ordered weights, 128*KTOT
    const ushort* __restrict__ hb,      // N x 64 bf16 layer input
    const int* __restrict__ srcv, const int* __restrict__ dstv,
    const float* __restrict__ attn, float* __restrict__ scv)
{
    constexpr int NK = GLOB ? 12 : 9;    // k-steps of 16: ef(4|1)+wni(4)+wnj(4)
    constexpr int KTOT = NK * 16;        // 192 / 144
    constexpr int EFR = GLOB ? 4 : 1;    // ef k-fragments
    constexpr int LDA = GLOB ? 64 : 16;
    __shared__ __align__(16) ushort As[128 * KTOT];
    const int tid = threadIdx.x;
    const int wid = tid >> 6, lane = tid & 63;
    const int hi = lane >> 5;            // k-half
    const int row = (blockIdx.x << 8) + (wid << 5) + (lane & 31);  // edge

    const int s_n = srcv[row];
    const int d_n = dstv[row];

    // B-operand fragments, all issued before the barrier
    bf16x8 bfr[NK];
#pragma unroll
    for (int t = 0; t < EFR; t++) {
        const float* ap = ef + (size_t)row * LDA + t * 16 + hi * 8;
        float4 f0 = *(const float4*)ap;
        float4 f1 = *(const float4*)(ap + 4);
        uint4 av;
        av.x = pk2(f0.x, f0.y); av.y = pk2(f0.z, f0.w);
        av.z = pk2(f1.x, f1.y); av.w = pk2(f1.z, f1.w);
        *(uint4*)&bfr[t] = av;
    }
#pragma unroll
    for (int t = 0; t < 4; t++)
        bfr[EFR + t] = *(const bf16x8*)(hb + (size_t)s_n * 64 + t * 16 + hi * 8);
#pragma unroll
    for (int t = 0; t < 4; t++)
        bfr[EFR + 4 + t] = *(const bf16x8*)(hb + (size_t)d_n * 64 + t * 16 + hi * 8);

    // stage fragment-ordered weights (straight copy, once per block)
    for (int i = tid; i < 128 * KTOT / 8; i += 512)
        *(uint4*)(As + (size_t)i * 8) = *(const uint4*)(Bfrag + (size_t)i * 8);
    __syncthreads();

    float ph[4];
#pragma unroll
    for (int c = 0; c < 4; c++) {        // ctile c == head c (32 f-dims)
        floatx16 acc;
#pragma unroll
        for (int r = 0; r < 16; r++) acc[r] = 0.f;
#pragma unroll
        for (int t = 0; t < NK; t++) {
            bf16x8 afr = *(const bf16x8*)(As + ((size_t)(c * NK + t) * 64 + lane) * 8);
            acc = __builtin_amdgcn_mfma_f32_32x32x16_bf16(afr, bfr[t], acc, 0, 0, 0);
        }
        // epilogue: row = (reg&3) + 8*(reg>>2) + 4*hi; attn flat 128
        float v = 0.f;
#pragma unroll
        for (int q = 0; q < 4; q++) {
            float4 at4 = *(const float4*)(attn + c * 32 + hi * 4 + q * 8);
            v = fmaf(lrelu02(acc[q * 4 + 0]), at4.x, v);
            v = fmaf(lrelu02(acc[q * 4 + 1]), at4.y, v);
            v = fmaf(lrelu02(acc[q * 4 + 2]), at4.z, v);
            v = fmaf(lrelu02(acc[q * 4 + 3]), at4.w, v);
        }
        ph[c] = v;
    }
#pragma unroll
    for (int h = 0; h < 4; h++) ph[h] += __shfl_xor(ph[h], 32);
    if (hi == 0)
        *(float4*)(scv + (size_t)row * 4) = make_float4(ph[0], ph[1], ph[2], ph[3]);
}

// ---------------------------------------------------------------------------
// Fused node + aggregation GEMM. Block = 64 nodes, 512 threads.
// Phase 1 (R21 node structure): 8-lane group per node; per edge, group loads
// scv/eidx/mask (broadcast) + 128B h[src]; per-element fmaf order identical
// to standalone node_fused -> identical z bits after f2b. z stored to LDS
// Zs[64][264] bf16 (row pad 264 -> 2-way bank alias on phase-2 reads, free).
// Bfold staged to Bs[64][264] concurrently. ONE barrier.
// Phase 2 (R20 gemm structure): 8 waves = 4 row-blocks x 2 ctile-pairs;
// A-fragments from Zs, B from Bs; kt-ascending accumulation identical to
// standalone gemm_agg -> bit-identical output. Invalid rows (n>=NN) are
// zero-filled in Zs and write-guarded.
// ---------------------------------------------------------------------------
__global__ __launch_bounds__(512, 2) void node_gemm(
    const float* __restrict__ scv,      // E x 4 fp32 (ORIGINAL edge order)
    const int* __restrict__ eidx,       // CSR position -> original edge
    const int* __restrict__ rowptr, const int* __restrict__ srcp,
    const float* __restrict__ maskp,
    const ushort* __restrict__ hsrc,    // N x 64 bf16 (layer input)
    const ushort* __restrict__ Bt,      // folded weights, 64 x 256
    const float* __restrict__ bias, int act,
    ushort* __restrict__ outb)          // N x 64 bf16
{
    __shared__ __align__(16) ushort Zs[64 * 264];
    __shared__ __align__(16) ushort Bs[64 * 264];
    const int tid = threadIdx.x;
    const int n0 = blockIdx.x << 6;

    // stage Bfold (independent of node phase; 4 iters of coalesced 16B)
    for (int idx = tid; idx < 64 * 32; idx += 512) {
        int r = idx >> 5, c8 = (idx & 31) << 3;
        *(uint4*)(Bs + r * 264 + c8) = *(const uint4*)(Bt + (size_t)r * 256 + c8);
    }

    // ---- phase 1: node softmax-aggregate (8 lanes per node) ----
    {
        int ln = tid >> 3, sl = tid & 7;       // node-local, dim-slice
        int n = n0 + ln;
        float l0 = 0.f, l1 = 0.f, l2 = 0.f, l3 = 0.f;
        float acc[4][8] = {};
        if (n < NN) {
            int beg = rowptr[n], end = rowptr[n + 1];
#pragma unroll 4
            for (int i = beg; i < end; i++) {
                int ep = eidx[i];                                    // broadcast
                float4 s4 = *(const float4*)(scv + (size_t)ep * 4);  // L2-resident
                float mk = maskp[i];
                int s = srcp[i];
                uint4 hvv = *(const uint4*)(hsrc + (size_t)s * 64 + sl * 8);
                float t0 = __expf(s4.x), t1 = __expf(s4.y), t2 = __expf(s4.z), t3 = __expf(s4.w);
                l0 += t0; l1 += t1; l2 += t2; l3 += t3;
                float a0 = t0 * mk, a1 = t1 * mk, a2 = t2 * mk, a3 = t3 * mk;
                float hv[8] = { b2f_lo(hvv.x), b2f_hi(hvv.x), b2f_lo(hvv.y), b2f_hi(hvv.y),
                                b2f_lo(hvv.z), b2f_hi(hvv.z), b2f_lo(hvv.w), b2f_hi(hvv.w) };
#pragma unroll
                for (int c = 0; c < 8; c++) {
                    acc[0][c] = fmaf(a0, hv[c], acc[0][c]);
                    acc[1][c] = fmaf(a1, hv[c], acc[1][c]);
                    acc[2][c] = fmaf(a2, hv[c], acc[2][c]);
                    acc[3][c] = fmaf(a3, hv[c], acc[3][c]);
                }
            }
        }
        float inv[4] = { 1.f / (l0 + 1e-9f), 1.f / (l1 + 1e-9f),
                         1.f / (l2 + 1e-9f), 1.f / (l3 + 1e-9f) };
#pragma unroll
        for (int h = 0; h < 4; h++) {
            uint4 o;
            o.x = pk2(acc[h][0] * inv[h], acc[h][1] * inv[h]);
            o.y = pk2(acc[h][2] * inv[h], acc[h][3] * inv[h]);
            o.z = pk2(acc[h][4] * inv[h], acc[h][5] * inv[h]);
            o.w = pk2(acc[h][6] * inv[h], acc[h][7] * inv[h]);
            *(uint4*)(Zs + ln * 264 + h * 64 + sl * 8) = o;
        }
    }
    __syncthreads();

    // ---- phase 2: z @ Bfold^T -> act -> outb (A from Zs, B from Bs) ----
    const int w = tid >> 6, lane = tid & 63;
    const int quad = lane >> 4, l16 = lane & 15;
    const int rw = w & 3, cp = w >> 2;          // row-block, ctile-pair

    floatx4 acc2[2];
#pragma unroll
    for (int cc = 0; cc < 2; cc++)
#pragma unroll
        for (int r = 0; r < 4; r++) acc2[cc][r] = 0.f;

#pragma unroll
    for (int kt = 0; kt < 8; kt++) {
        bf16x8 af = *(const bf16x8*)(Zs + (16 * rw + l16) * 264 + kt * 32 + quad * 8);
#pragma unroll
        for (int cc = 0; cc < 2; cc++) {
            bf16x8 bfv = *(const bf16x8*)(Bs + (16 * (2 * cp + cc) + l16) * 264 + kt * 32 + quad * 8);
            acc2[cc] = __builtin_amdgcn_mfma_f32_16x16x32_bf16(af, bfv, acc2[cc], 0, 0, 0);
        }
    }
#pragma unroll
    for (int r = 0; r < 4; r++) {
        int gr = n0 + 16 * rw + quad * 4 + r;
        if (gr < NN) {
#pragma unroll
            for (int cc = 0; cc < 2; cc++) {
                int col = 16 * (2 * cp + cc) + l16;
                float v = acc2[cc][r] + bias[col];
                if (act == 0) v = v > 0.f ? v : (__expf(v) - 1.f);
                else          v = v > 0.f ? v : 0.01f * v;
                outb[(size_t)gr * 64 + col] = f2b(v);
            }
        }
    }
}

// ---------------------------------------------------------------------------
// Deterministic CSR build: histogram -> scan -> atomic rank scatter (eidx only)
// -> per-node insertion sort (original-index order).
// ---------------------------------------------------------------------------
__global__ void k_count(const int* __restrict__ dst, int* __restrict__ deg, int E)
{
    for (int i = blockIdx.x * blockDim.x + threadIdx.x; i < E; i += gridDim.x * blockDim.x)
        atomicAdd(&deg[dst[i]], 1);
}

__global__ __launch_bounds__(256) void scan_local(
    const int* __restrict__ deg, int* __restrict__ rowptr, int* __restrict__ partials, int N)
{
    __shared__ int sd[256];
    int tid = threadIdx.x;
    int i = blockIdx.x * 256 + tid;
    int v = (i < N) ? deg[i] : 0;
    sd[tid] = v; __syncthreads();
#pragma unroll
    for (int off = 1; off < 256; off <<= 1) {
        int t = (tid >= off) ? sd[tid - off] : 0;
        __syncthreads();
        sd[tid] += t;
        __syncthreads();
    }
    if (i < N) rowptr[i] = sd[tid] - v;
    if (tid == 255) partials[blockIdx.x] = sd[255];
}

__global__ __launch_bounds__(256) void scan_partials(int* __restrict__ partials, int nb)
{
    __shared__ int sd[256];
    int tid = threadIdx.x;
    int v = (tid < nb) ? partials[tid] : 0;
    sd[tid] = v; __syncthreads();
#pragma unroll
    for (int off = 1; off < 256; off <<= 1) {
        int t = (tid >= off) ? sd[tid - off] : 0;
        __syncthreads();
        sd[tid] += t;
        __syncthreads();
    }
    if (tid < nb) partials[tid] = sd[tid] - v;
}

__global__ void scan_add(int* __restrict__ rowptr, const int* __restrict__ partials, int N, int E)
{
    int i = blockIdx.x * 256 + threadIdx.x;
    if (i < N) rowptr[i] += partials[i >> 8];
    if (i == 0) rowptr[N] = E;
}

__global__ void k_scatter(const int* __restrict__ dst, const int* __restrict__ rowptr,
                          int* __restrict__ cnt, int* __restrict__ eidx, int E)
{
    for (int i = blockIdx.x * blockDim.x + threadIdx.x; i < E; i += gridDim.x * blockDim.x) {
        int d = dst[i];
        int p = rowptr[d] + atomicAdd(&cnt[d], 1);
        eidx[p] = i;
    }
}

// one thread per node: insertion-sort its bucket ascending (deterministic,
// matches reference's index-order segment sums). Avg degree 6.4.
__global__ void k_sort_buckets(const int* __restrict__ rowptr, int* __restrict__ eidx, int N)
{
    int n = blockIdx.x * blockDim.x + threadIdx.x;
    if (n >= N) return;
    int beg = rowptr[n], end = rowptr[n + 1];
    for (int i = beg + 1; i < end; i++) {
        int v = eidx[i];
        int j = i - 1;
        while (j >= beg && eidx[j] > v) { eidx[j + 1] = eidx[j]; j--; }
        eidx[j + 1] = v;
    }
}

// small permute: per CSR position p, pull src/masks (L2-resident gathers).
__global__ void k_perm_small(const int* __restrict__ eidx, const int* __restrict__ src,
                             const float* __restrict__ m1, const float* __restrict__ m2,
                             int* __restrict__ srcp, float* __restrict__ m1p,
                             float* __restrict__ m2p, int E)
{
    int p = blockIdx.x * blockDim.x + threadIdx.x;
    if (p < E) {
        int e = eidx[p];
        srcp[p] = src[e];
        m1p[p] = m1[e];
        m2p[p] = m2[e];
    }
}

__global__ void k_cvt(const float* __restrict__ in, ushort* __restrict__ out, int n)
{
    for (int i = blockIdx.x * blockDim.x + threadIdx.x; i < n; i += gridDim.x * blockDim.x)
        out[i] = f2b(in[i]);
}

// ---------------------------------------------------------------------------
// Weight prep for the 32x32x16 score kernel. Bsc[e] fragment order: out index
// o -> j=o&7, lane=(o>>3)&63, tf=o>>9, c=tf/NK, t=tf%NK; m=32c+(lane&31),
// k=16t+8*(lane>>5)+j. Columns: [we(ef_end)|wni(64)|wnj(64)].
// glob: NK=12 (KTOT 192); loc: NK=9 (KTOT 144, no pad).
// ---------------------------------------------------------------------------
__global__ void k_prep_score_all(const float* __restrict__ loc_we, const float* __restrict__ glob_we,
                                 const float* __restrict__ loc_wni, const float* __restrict__ glob_wni,
                                 const float* __restrict__ loc_wnj, const float* __restrict__ glob_wnj,
                                 ushort* __restrict__ B)   // 4 x 24576 slots
{
    int idx = blockIdx.x * 256 + threadIdx.x;   // 4*24576 = 98304
    if (idx >= 4 * 24576) return;
    int e = idx / 24576, rem = idx % 24576;
    int layer = e >> 1, gl = e & 1;
    int NK = gl ? 12 : 9;
    int KTOT = NK * 16;
    int ef_end = gl ? 64 : 16;
    if (rem >= 128 * KTOT) return;
    int j = rem & 7, lane = (rem >> 3) & 63, tf = rem >> 9;
    int c = tf / NK, t = tf % NK;
    int m = 32 * c + (lane & 31);
    int k = 16 * t + 8 * (lane >> 5) + j;
    const float* we  = (gl ? glob_we  + layer * 64 * 128 : loc_we  + layer * 16 * 128);
    const float* wni = (gl ? glob_wni : loc_wni) + layer * 64 * 128;
    const float* wnj = (gl ? glob_wnj : loc_wnj) + layer * 64 * 128;
    float v;
    if (k < ef_end)            v = we[k * 128 + m];
    else if (k < ef_end + 64)  v = wni[(k - ef_end) * 128 + m];
    else                       v = wnj[(k - ef_end - 64) * 128 + m];
    B[e * 24576 + rem] = f2b(v);
}

// W'[h*64+i, j] = sum_k wnode[i, h*64+k] * aggw[h*64+k, j]; stored transposed (64 x 256)
__global__ void k_fold_all(const float* __restrict__ loc_wnode, const float* __restrict__ agg1_w,
                           const float* __restrict__ glob_wnode, const float* __restrict__ agg2_w,
                           ushort* __restrict__ B)  // 4 x (64 x 256)
{
    int e = blockIdx.x >> 6;
    int idx = (blockIdx.x & 63) * 256 + threadIdx.x;  // 16384
    int layer = e >> 1, gl = e & 1;
    const float* wnode = (gl ? glob_wnode : loc_wnode) + layer * 64 * 256;
    const float* aggw  = (gl ? agg2_w : agg1_w) + layer * 256 * 64;
    int j = idx >> 8, col = idx & 255;
    int h = col >> 6, ii = col & 63;
    float s = 0.f;
#pragma unroll 8
    for (int k = 0; k < 64; k++)
        s = fmaf(wnode[ii * 256 + h * 64 + k], aggw[(h * 64 + k) * 64 + j], s);
    B[e * 16384 + j * 256 + col] = f2b(s);
}

// ---------------------------------------------------------------------------
// Final MLP heads. One wave per batch row.
// ---------------------------------------------------------------------------
__global__ __launch_bounds__(256) void final_ui(
    const ushort* __restrict__ s0, const ushort* __restrict__ s1,
    const int* __restrict__ uidx, const int* __restrict__ iidx,
    const float* __restrict__ w1, const float* __restrict__ b1,
    const float* __restrict__ w2, const float* __restrict__ b2, float* __restrict__ out)
{
    __shared__ float xs[4][256];
    int tid = threadIdx.x, wid = tid >> 6, lane = tid & 63;
    int r = (blockIdx.x << 2) + wid;
    int u = uidx[r], it = iidx[r];
    xs[wid][lane]       = b2f(s0[(size_t)u * 64 + lane]);
    xs[wid][64 + lane]  = b2f(s1[(size_t)u * 64 + lane]);
    xs[wid][128 + lane] = b2f(s0[(size_t)it * 64 + lane]);
    xs[wid][192 + lane] = b2f(s1[(size_t)it * 64 + lane]);
    __syncthreads();
    int c = lane << 1;
    float a0 = b1[c], a1 = b1[c + 1];
    for (int k = 0; k < 256; k++) {
        float xv = xs[wid][k];
        float2 wv = *(const float2*)(w1 + (size_t)k * 128 + c);
        a0 = fmaf(xv, wv.x, a0);
        a1 = fmaf(xv, wv.y, a1);
    }
    a0 = fmaxf(a0, 0.f);
    a1 = fmaxf(a1, 0.f);
    float2 w2v = *(const float2*)(w2 + c);
    float p = a0 * w2v.x + a1 * w2v.y;
#pragma unroll
    for (int mm = 1; mm < 64; mm <<= 1) p += __shfl_xor(p, mm);
    if (lane == 0) out[r] = 1.f / (1.f + __expf(-(p + b2[0])));
}

__global__ __launch_bounds__(256) void final_sg(
    const ushort* __restrict__ s0, const ushort* __restrict__ s1,
    const int* __restrict__ gidx,
    const float* __restrict__ w1, const float* __restrict__ b1,
    const float* __restrict__ w2, const float* __restrict__ b2, float* __restrict__ out)
{
    __shared__ float xs[4][128];
    int tid = threadIdx.x, wid = tid >> 6, lane = tid & 63;
    int r = (blockIdx.x << 2) + wid;
    int n = gidx[r];
    xs[wid][lane]      = b2f(s0[(size_t)n * 64 + lane]);
    xs[wid][64 + lane] = b2f(s1[(size_t)n * 64 + lane]);
    __syncthreads();
    int c = lane << 1;
    float a0 = b1[c], a1 = b1[c + 1];
    for (int k = 0; k < 128; k++) {
        float xv = xs[wid][k];
        float2 wv = *(const float2*)(w1 + (size_t)k * 128 + c);
        a0 = fmaf(xv, wv.x, a0);
        a1 = fmaf(xv, wv.y, a1);
    }
    a0 = fmaxf(a0, 0.f);
    a1 = fmaxf(a1, 0.f);
    float2 w2v = *(const float2*)(w2 + c);
    float p = a0 * w2v.x + a1 * w2v.y;
#pragma unroll
    for (int mm = 1; mm < 64; mm <<= 1) p += __shfl_xor(p, mm);
    if (lane == 0) out[r] = 1.f / (1.f + __expf(-(p + b2[0])));
}

// ---------------------------------------------------------------------------
extern "C" void kernel_launch(void* const* d_in, const int* in_sizes, int n_in,
                              void* d_out, int out_size, void* d_ws, size_t ws_size,
                              hipStream_t stream)
{
    const float* x       = (const float*)d_in[0];
    const float* efeat   = (const float*)d_in[1];
    const float* efeat2  = (const float*)d_in[2];
    const float* mask1   = (const float*)d_in[3];
    const float* mask2   = (const float*)d_in[4];
    const int*   src     = (const int*)d_in[5];
    const int*   dst     = (const int*)d_in[6];
    const int*   uidx    = (const int*)d_in[7];
    const int*   iidx    = (const int*)d_in[8];
    const int*   gidx    = (const int*)d_in[9];
    const float* loc_wni = (const float*)d_in[10];
    const float* loc_wnj = (const float*)d_in[11];
    const float* loc_we  = (const float*)d_in[12];
    const float* loc_attn= (const float*)d_in[13];
    const float* loc_wnode=(const float*)d_in[14];
    const float* agg1_w  = (const float*)d_in[15];
    const float* agg1_b  = (const float*)d_in[16];
    const float* glob_wni= (const float*)d_in[17];
    const float* glob_wnj= (const float*)d_in[18];
    const float* glob_we = (const float*)d_in[19];
    const float* glob_attn=(const float*)d_in[20];
    const float* glob_wnode=(const float*)d_in[21];
    const float* agg2_w  = (const float*)d_in[22];
    const float* agg2_b  = (const float*)d_in[23];
    const float* w1_ui   = (const float*)d_in[24];
    const float* b1_ui   = (const float*)d_in[25];
    const float* w1_sg   = (const float*)d_in[26];
    const float* b1_sg   = (const float*)d_in[27];
    const float* w2_ui   = (const float*)d_in[28];
    const float* b2_ui   = (const float*)d_in[29];
    const float* w2_sg   = (const float*)d_in[30];
    const float* b2_sg   = (const float*)d_in[31];

    // workspace carve (all offsets 256B-aligned)
    char* wsp = (char*)d_ws;
    auto carve = [&](size_t bytes) { char* p = wsp; wsp += (bytes + 255) & ~(size_t)255; return p; };
    ushort* hb[5];
    for (int i = 0; i < 5; i++) hb[i] = (ushort*)carve((size_t)NN * 64 * 2);
    float*  scv   = (float*)carve((size_t)NE * 16);
    float*  m1p   = (float*)carve((size_t)NE * 4);
    float*  m2p   = (float*)carve((size_t)NE * 4);
    int*    srcp  = (int*)carve((size_t)NE * 4);
    int*    eidx  = (int*)carve((size_t)NE * 4);
    ushort* Bsc   = (ushort*)carve(4 * 24576 * 2);
    ushort* Bfold = (ushort*)carve(4 * 16384 * 2);
    int* deg      = (int*)carve(NN * 4);
    int* rowptr   = (int*)carve((NN + 4) * 4);
    int* partials = (int*)carve(256 * 4);

    // ---- weight prep (state-independent) + deterministic CSR build ----
    k_prep_score_all<<<384, 256, 0, stream>>>(loc_we, glob_we, loc_wni, glob_wni,
                                              loc_wnj, glob_wnj, Bsc);
    k_fold_all<<<256, 256, 0, stream>>>(loc_wnode, agg1_w, glob_wnode, agg2_w, Bfold);
    hipMemsetAsync(deg, 0, NN * sizeof(int), stream);
    k_count<<<1280, 256, 0, stream>>>(dst, deg, NE);
    scan_local<<<196, 256, 0, stream>>>(deg, rowptr, partials, NN);
    scan_partials<<<1, 256, 0, stream>>>(partials, 196);
    scan_add<<<196, 256, 0, stream>>>(rowptr, partials, NN, NE);
    hipMemsetAsync(deg, 0, NN * sizeof(int), stream);
    k_scatter<<<1280, 256, 0, stream>>>(dst, rowptr, deg, eidx, NE);
    k_sort_buckets<<<196, 256, 0, stream>>>(rowptr, eidx, NN);
    k_perm_small<<<1250, 256, 0, stream>>>(eidx, src, mask1, mask2,
                                           srcp, m1p, m2p, NE);
    k_cvt<<<3200, 256, 0, stream>>>(x, hb[0], NN * 64);

    auto egat = [&](const ushort* hin, int e, const float* maskp, const float* attn,
                    const float* aggb, int act, ushort* hout) {
        int is_glob = e & 1;
        if (is_glob)
            score32<1><<<1250, 512, 0, stream>>>(efeat2, Bsc + e * 24576, hin,
                                                 src, dst, attn, scv);
        else
            score32<0><<<1250, 512, 0, stream>>>(efeat, Bsc + e * 24576, hin,
                                                 src, dst, attn, scv);
        node_gemm<<<(NN + 63) / 64, 512, 0, stream>>>(scv, eidx, rowptr, srcp, maskp,
                                                      hin, Bfold + e * 16384, aggb,
                                                      act, hout);
    };

    egat(hb[0], 0, m1p, loc_attn,        agg1_b,      0, hb[1]);
    egat(hb[1], 1, m2p, glob_attn,       agg2_b,      1, hb[2]);
    egat(hb[2], 2, m1p, loc_attn + 128,  agg1_b + 64, 0, hb[3]);
    egat(hb[3], 3, m2p, glob_attn + 128, agg2_b + 64, 1, hb[4]);

    float* out = (float*)d_out;
    final_sg<<<BATCH / 4, 256, 0, stream>>>(hb[2], hb[4], gidx, w1_sg, b1_sg, w2_sg, b2_sg, out);
    final_ui<<<BATCH / 4, 256, 0, stream>>>(hb[1], hb[3], uidx, iidx, w1_ui, b1_ui, w2_ui, b2_ui, out + BATCH);
}